// Round 5
// baseline (511.787 us; speedup 1.0000x reference)
//
#include <hip/hip_runtime.h>

// out[b, n] = sum_k x[b,k] * w[n,k];  B=8, K=4096, N=11008, fp32.
// HBM floor: 180.4 MB weight stream / 6.3 TB/s ~= 29 us.
// Round-5: one row per wave (one sequential 16 KB weight stream per wave),
// x staged in LDS in 2 x 64 KB chunks shared by all 8 waves. Per k-step:
// 1 weight float4 load + 8 conflict-free ds_read_b128 + 32 FMA.
// BLOCK=512, 64 KB LDS -> 2 blocks/CU resident (16 waves/CU), so barrier
// drains in one block overlap compute in the other. No nontemporal loads,
// no manual pipeline (round-4's divergence suspects reverted).

typedef float f32x4 __attribute__((ext_vector_type(4)));

#define BATCH  8
#define KDIM   4096
#define NDIM   11008
#define K4     (KDIM / 4)      // 1024 float4 per row
#define NCHUNK 2
#define KC4    (K4 / NCHUNK)   // 512 float4 per batch per chunk
#define BLOCK  512
#define WAVES  (BLOCK / 64)    // 8 waves -> 8 rows per block
#define STEPS  (KC4 / 64)      // 8 lane-strided steps per chunk

__global__ __launch_bounds__(BLOCK)
void ActivationSparseLinear_4982162063725_kernel(const float* __restrict__ x,
                                                 const float* __restrict__ w,
                                                 float* __restrict__ out) {
    __shared__ f32x4 xs[BATCH * KC4];   // 4096 f32x4 = 64 KB

    const int tid  = threadIdx.x;
    const int lane = tid & 63;
    const int wave = tid >> 6;
    const int n    = blockIdx.x * WAVES + wave;   // one output row per wave

    const f32x4* x4   = (const f32x4*)x;          // [BATCH][K4]
    const f32x4* wrow = (const f32x4*)w + (size_t)n * K4;

    float acc[BATCH];
#pragma unroll
    for (int b = 0; b < BATCH; ++b) acc[b] = 0.0f;

    for (int c = 0; c < NCHUNK; ++c) {
        if (c) __syncthreads();                   // xs reuse guard

        // Stage x[:, chunk c] into LDS: 4096 f32x4 over 512 threads = 8 each,
        // each pass a fully-coalesced 512-lane float4 load (x is L2/L3-hot).
#pragma unroll
        for (int i = 0; i < (BATCH * KC4) / BLOCK; ++i) {
            const int idx = i * BLOCK + tid;
            const int b   = idx >> 9;             // / KC4
            const int off = idx & (KC4 - 1);
            xs[idx] = x4[b * K4 + c * KC4 + off];
        }
        __syncthreads();

#pragma unroll
        for (int j = 0; j < STEPS; ++j) {
            const f32x4 wv = wrow[c * KC4 + j * 64 + lane];  // 1 KB/wave, sequential stream
#pragma unroll
            for (int b = 0; b < BATCH; ++b) {
                const f32x4 xv = xs[b * KC4 + j * 64 + lane]; // ds_read_b128, conflict-free
                acc[b] += wv.x * xv.x + wv.y * xv.y + wv.z * xv.z + wv.w * xv.w;
            }
        }
    }

    // Butterfly-reduce the 8 batch partials across the wave; lane 0 stores.
#pragma unroll
    for (int b = 0; b < BATCH; ++b) {
        float v = acc[b];
#pragma unroll
        for (int off = 32; off > 0; off >>= 1)
            v += __shfl_xor(v, off, 64);
        if (lane == 0)
            out[(size_t)b * NDIM + n] = v;
    }
}

extern "C" void kernel_launch(void* const* d_in, const int* in_sizes, int n_in,
                              void* d_out, int out_size, void* d_ws, size_t ws_size,
                              hipStream_t stream) {
    const float* x = (const float*)d_in[0];   // (8, 1, 4096) fp32
    const float* w = (const float*)d_in[1];   // (11008, 4096) fp32
    float* out = (float*)d_out;               // (8, 1, 11008) fp32

    dim3 grid(NDIM / WAVES);                  // 1376 blocks, exact fit
    ActivationSparseLinear_4982162063725_kernel<<<grid, BLOCK, 0, stream>>>(x, w, out);
}